// Round 14
// baseline (165.818 us; speedup 1.0000x reference)
//
#include <hip/hip_runtime.h>
#include <stdint.h>

#define B_SZ 4
#define T_SZ 2048
#define H_SZ 16
#define D_SZ 64
#define C_SZ 1024
#define N3_SZ 3072
#define M_SZ (B_SZ * T_SZ) // 8192

using bf16x8 = __attribute__((ext_vector_type(8))) __bf16;
using f32x4  = __attribute__((ext_vector_type(4))) float;
using f32x16 = __attribute__((ext_vector_type(16))) float;
using uivec2 = __attribute__((ext_vector_type(2))) unsigned int;
using uivec4 = __attribute__((ext_vector_type(4))) unsigned int;

__device__ __forceinline__ unsigned short f2bf(float f) {
    union { float f; unsigned int u; } v; v.f = f;
    unsigned int r = v.u + 0x7FFFu + ((v.u >> 16) & 1u);
    return (unsigned short)(r >> 16);
}
__device__ __forceinline__ unsigned int pack_bf2(float lo, float hi) {
    return (unsigned int)f2bf(lo) | ((unsigned int)f2bf(hi) << 16);
}

__device__ __forceinline__ void async16(const void* g, void* l) {
    __builtin_amdgcn_global_load_lds((const __attribute__((address_space(1))) void*)g,
                                     (__attribute__((address_space(3))) void*)l, 16, 0, 0);
}
__device__ __forceinline__ f32x4 mfma16(bf16x8 a, bf16x8 b, f32x4 c) {
    return __builtin_amdgcn_mfma_f32_16x16x32_bf16(a, b, c, 0, 0, 0);
}
__device__ __forceinline__ f32x16 mfma32(bf16x8 a, bf16x8 b, f32x16 c) {
    return __builtin_amdgcn_mfma_f32_32x32x16_bf16(a, b, c, 0, 0, 0);
}
__device__ __forceinline__ f32x16 zero16() {
    f32x16 z;
#pragma unroll
    for (int i = 0; i < 16; i++) z[i] = 0.f;
    return z;
}

// ---------------- fused prologue: x->bf16, both weight transposes, rope table ----------
__global__ __launch_bounds__(256) void k_prologue(const float4* __restrict__ x,
                                                  uint2* __restrict__ xb,
                                                  const float* __restrict__ w_qkv,
                                                  unsigned short* __restrict__ wqkvT,
                                                  const float* __restrict__ w_out,
                                                  unsigned short* __restrict__ woutT,
                                                  float* __restrict__ rtab) {
    __shared__ float tile[32][33];
    const int bid = blockIdx.x;
    const int tid = threadIdx.x;
    if (bid < 2048) {
        const int n4 = M_SZ * C_SZ / 4;
        for (int i = bid * 256 + tid; i < n4; i += 2048 * 256) {
            float4 v = x[i];
            uint2 o;
            o.x = pack_bf2(v.x, v.y);
            o.y = pack_bf2(v.z, v.w);
            xb[i] = o;
        }
    } else if (bid < 2048 + 3072) {
        const int t = bid - 2048;
        const int n0 = (t % (N3_SZ / 32)) * 32, k0 = (t / (N3_SZ / 32)) * 32;
        const int tx = tid & 31, ty = tid >> 5;
#pragma unroll
        for (int j = 0; j < 32; j += 8)
            tile[ty + j][tx] = w_qkv[(size_t)(k0 + ty + j) * N3_SZ + (n0 + tx)];
        __syncthreads();
#pragma unroll
        for (int j = 0; j < 32; j += 8)
            wqkvT[(size_t)(n0 + ty + j) * C_SZ + (k0 + tx)] = f2bf(tile[tx][ty + j]);
    } else if (bid < 2048 + 3072 + 1024) {
        const int t = bid - (2048 + 3072);
        const int n0 = (t % (C_SZ / 32)) * 32, k0 = (t / (C_SZ / 32)) * 32;
        const int tx = tid & 31, ty = tid >> 5;
#pragma unroll
        for (int j = 0; j < 32; j += 8)
            tile[ty + j][tx] = w_out[(size_t)(k0 + ty + j) * C_SZ + (n0 + tx)];
        __syncthreads();
#pragma unroll
        for (int j = 0; j < 32; j += 8)
            woutT[(size_t)(n0 + ty + j) * C_SZ + (k0 + tx)] = f2bf(tile[tx][ty + j]);
    } else {
        const int i = (bid - (2048 + 3072 + 1024)) * 256 + tid;
        if (i < T_SZ * 32) {
            int t = i >> 5, fq = i & 31;
            float invf = powf(10000.0f, -(float)fq / 32.0f);
            float ang = (float)t * invf;
            rtab[t * 64 + fq * 2]     = cosf(ang);
            rtab[t * 64 + fq * 2 + 1] = sinf(ang);
        }
    }
}

// ==== GEMM body: 128x256, BK=32, DOUBLE-buffer 48KB -> 3 blocks/CU, 1 barrier/tile ====
// One-ahead staging (tile t+1 into buf nx while computing buf cur). vmcnt(0) drain per
// tile is hidden by 3 co-resident blocks (m97/m114 mechanism). 1 barrier/tile is safe:
// barrier at t-1 end guarantees all waves done reading nx's old data before restage;
// per-wave vmcnt(0) before that barrier guarantees cur's data landed.
#define GEMM_BODY(Kdim)                                                                    \
    const int tid = threadIdx.x;                                                           \
    const int wave = tid >> 6, lane = tid & 63;                                            \
    const int lcol = lane & 15, lrow = lane >> 4;                                          \
    const int wm = wave >> 2, wn = wave & 3;                                               \
    const int Kd_ = (Kdim);                                                                \
    const int srow = tid >> 2;                                                             \
    const int schs = (tid & 3) ^ ((tid >> 3) & 3);                                         \
    const unsigned short* Asrc = A + (size_t)(m0 + srow) * Kd_ + schs * 8;                 \
    const unsigned short* Bsrc = BT + (size_t)(n0 + srow) * Kd_ + schs * 8;                \
    const int swz = (lrow ^ ((lcol >> 1) & 3)) * 8;                                        \
    f32x4 acc[4][4];                                                                       \
    _Pragma("unroll") for (int i = 0; i < 4; i++)                                          \
        _Pragma("unroll") for (int j = 0; j < 4; j++) acc[i][j] = (f32x4){0.f,0.f,0.f,0.f};\
    SU_B(0, 0, 0); SU_B(0, 1, 0); SU_A(0, 0);                                              \
    asm volatile("s_waitcnt vmcnt(0)" ::: "memory");                                       \
    __builtin_amdgcn_s_barrier();                                                          \
    const int NT = Kd_ >> 5;                                                               \
    for (int t = 0; t < NT; ++t) {                                                         \
        const int cur = t & 1, nx = cur ^ 1;                                               \
        const unsigned short* Acur = As + cur * 4096;                                      \
        const unsigned short* Bcur = Bs + cur * 8192;                                      \
        const size_t kn = (size_t)(t + 1) * 32;                                            \
        const bool more = (t + 1 < NT);                                                    \
        bf16x8 a0 = LD_A(0), a1 = LD_A(1), a2 = LD_A(2), a3 = LD_A(3);                     \
        bf16x8 b0 = LD_B(0), b1 = LD_B(1), b2 = LD_B(2), b3 = LD_B(3);                     \
        if (more) { SU_B(nx, 0, kn); SU_B(nx, 1, kn); SU_A(nx, kn); }                      \
        asm volatile("s_waitcnt lgkmcnt(0)" ::: "memory");                                 \
        __builtin_amdgcn_sched_barrier(0);                                                 \
        __builtin_amdgcn_s_setprio(1);                                                     \
        acc[0][0] = mfma16(a0, b0, acc[0][0]);                                             \
        acc[0][1] = mfma16(a0, b1, acc[0][1]);                                             \
        acc[0][2] = mfma16(a0, b2, acc[0][2]);                                             \
        acc[0][3] = mfma16(a0, b3, acc[0][3]);                                             \
        acc[1][0] = mfma16(a1, b0, acc[1][0]);                                             \
        acc[1][1] = mfma16(a1, b1, acc[1][1]);                                             \
        acc[1][2] = mfma16(a1, b2, acc[1][2]);                                             \
        acc[1][3] = mfma16(a1, b3, acc[1][3]);                                             \
        acc[2][0] = mfma16(a2, b0, acc[2][0]);                                             \
        acc[2][1] = mfma16(a2, b1, acc[2][1]);                                             \
        acc[2][2] = mfma16(a2, b2, acc[2][2]);                                             \
        acc[2][3] = mfma16(a2, b3, acc[2][3]);                                             \
        acc[3][0] = mfma16(a3, b0, acc[3][0]);                                             \
        acc[3][1] = mfma16(a3, b1, acc[3][1]);                                             \
        acc[3][2] = mfma16(a3, b2, acc[3][2]);                                             \
        acc[3][3] = mfma16(a3, b3, acc[3][3]);                                             \
        __builtin_amdgcn_s_setprio(0);                                                     \
        asm volatile("s_waitcnt vmcnt(0)" ::: "memory");                                   \
        __builtin_amdgcn_s_barrier();                                                      \
    }

// As: [2][128*32] (8KB each); Bs: [2][256*32] (16KB each, unit q = 128 rows)
#define SU_A(BI, KO) async16(Asrc + (KO), As + (BI) * 4096 + tid * 8)
#define SU_B(BI, Q, KO) async16(Bsrc + (size_t)(Q) * 128 * Kd_ + (KO), \
                                Bs + (BI) * 8192 + (Q) * 4096 + tid * 8)
#define LD_A(MF) (*reinterpret_cast<const bf16x8*>( \
    Acur + (wm * 64 + (MF) * 16 + lcol) * 32 + swz))
#define LD_B(NF) (*reinterpret_cast<const bf16x8*>( \
    Bcur + (wn * 64 + (NF) * 16 + lcol) * 32 + swz))

// ---------------- QKV GEMM: fused RoPE epilogue; Q/K planes + direct-transposed V -------
__global__ __launch_bounds__(512, 3) void k_gemmqkv(const unsigned short* __restrict__ A,
                                                    const unsigned short* __restrict__ BT,
                                                    const float* __restrict__ bias,
                                                    unsigned short* __restrict__ qp,
                                                    unsigned short* __restrict__ kp,
                                                    unsigned short* __restrict__ vtp,
                                                    const float* __restrict__ rtab) {
    extern __shared__ unsigned short lds[];
    unsigned short* As = lds;               // [2][128*32]
    unsigned short* Bs = lds + 2 * 4096;    // [2][256*32]
    int orig = blockIdx.x + gridDim.x * blockIdx.y; // 0..767
    int lin = (orig & 7) * 96 + (orig >> 3);
    const int n0 = (lin % 12) * 256, m0 = (lin / 12) * 128;
    GEMM_BODY(C_SZ)

    const int cb = n0 + wn * 64; // wave col span == one head
    float bv[4];
#pragma unroll
    for (int nf = 0; nf < 4; nf++) bv[nf] = bias[cb + nf * 16 + lcol];
    if (cb < 2 * C_SZ) {
        const float scl = (cb < C_SZ) ? 0.125f * 1.4426950408889634f : 1.0f;
        unsigned short* dst = (cb < C_SZ) ? qp : kp;
        const int cbl = cb & (C_SZ - 1);
#pragma unroll
        for (int mf = 0; mf < 4; mf++) {
#pragma unroll
            for (int r = 0; r < 4; r++) {
                int row = m0 + wm * 64 + mf * 16 + lrow * 4 + r;
                int t = row & (T_SZ - 1);
#pragma unroll
                for (int p = 0; p < 2; p++) {
                    int fq = p * 16 + lcol;
                    float2 cs = *(const float2*)(rtab + t * 64 + fq * 2);
                    float a  = acc[mf][p][r]     + bv[p];
                    float bb = acc[mf][p + 2][r] + bv[p + 2];
                    float lo = (a * cs.x - bb * cs.y) * scl;
                    float hi = (bb * cs.x + a * cs.y) * scl;
                    dst[(size_t)row * C_SZ + cbl + fq]      = f2bf(lo);
                    dst[(size_t)row * C_SZ + cbl + fq + 32] = f2bf(hi);
                }
            }
        }
    } else {
        // V: direct transposed store to vtp[bh][d][t]
        const int hh = (cb - 2 * C_SZ) >> 6;
        const int bb = m0 >> 11;
        const int bhv = bb * H_SZ + hh;
        const int t0w = (m0 & (T_SZ - 1)) + wm * 64;
#pragma unroll
        for (int nf = 0; nf < 4; nf++) {
            const int d = nf * 16 + lcol;
            unsigned short* vrow = vtp + ((size_t)bhv * 64 + d) * T_SZ + t0w;
#pragma unroll
            for (int mf = 0; mf < 4; mf++) {
                int t = mf * 16 + lrow * 4;
                uint2 o;
                o.x = pack_bf2(acc[mf][nf][0] + bv[nf], acc[mf][nf][1] + bv[nf]);
                o.y = pack_bf2(acc[mf][nf][2] + bv[nf], acc[mf][nf][3] + bv[nf]);
                *(uint2*)(vrow + t) = o;
            }
        }
    }
}

// ---------------- out-proj GEMM: 128x256, f32 + bias epilogue ----------------
__global__ __launch_bounds__(512, 3) void k_gemmout(const unsigned short* __restrict__ A,
                                                    const unsigned short* __restrict__ BT,
                                                    const float* __restrict__ bias,
                                                    float* __restrict__ Cout) {
    extern __shared__ unsigned short lds[];
    unsigned short* As = lds;
    unsigned short* Bs = lds + 2 * 4096;
    int orig = blockIdx.x + gridDim.x * blockIdx.y; // 0..255
    int lin = (orig & 7) * 32 + (orig >> 3);
    const int n0 = (lin % 4) * 256, m0 = (lin / 4) * 128;
    GEMM_BODY(C_SZ)
    const int cb = n0 + wn * 64;
#pragma unroll
    for (int nf = 0; nf < 4; nf++) {
        int col = cb + nf * 16 + lcol;
        float bv = bias[col];
#pragma unroll
        for (int mf = 0; mf < 4; mf++) {
#pragma unroll
            for (int r = 0; r < 4; r++) {
                int row = m0 + wm * 64 + mf * 16 + lrow * 4 + r;
                Cout[(size_t)row * C_SZ + col] = acc[mf][nf][r] + bv;
            }
        }
    }
}

#undef SU_A
#undef SU_B
#undef LD_A
#undef LD_B

// ---------------- causal flash attention (v5r: paired q-tiles, 8 waves, 32KB LDS) -------
__global__ __launch_bounds__(512, 4) void k_attn(const unsigned short* __restrict__ qp,
                                                 const unsigned short* __restrict__ kp,
                                                 const unsigned short* __restrict__ vtp,
                                                 unsigned short* __restrict__ attn_out) {
    __shared__ __align__(16) unsigned short lds[16384]; // [K0|V0|K1|V1] 4x8KB; Q overlay
    int orig = blockIdx.x + gridDim.x * blockIdx.y;     // grid (8,64) = 512
    int lin = (orig & 7) * 64 + (orig >> 3);            // 8 bh per XCD
    const int pr = lin & 7, bh = lin >> 3;
    const int b = bh >> 4, h = bh & 15;
    const int qtA = pr, qtB = 15 - pr;
    const int tid = threadIdx.x;
    const int w = tid >> 6, lane = tid & 63;
    const int l31 = lane & 31, hi = lane >> 5;
    const int sx = l31 & 7;
    const int wsel = w >> 2;
    const int wq0 = (wsel ? qtB : qtA) * 128 + (w & 3) * 32;
    const int qg = wq0 + l31;

#pragma unroll
    for (int L = 0; L < 4; L++) {
        int flat = L * 512 + tid;
        int row = flat >> 3, ch = flat & 7;
        int qrow = (row < 128) ? (qtA * 128 + row) : (qtB * 128 + row - 128);
        int chs = ch ^ (row & 7);
        async16(qp + ((size_t)(b * T_SZ + qrow)) * C_SZ + h * D_SZ + chs * 8, lds + flat * 8);
    }
    asm volatile("s_waitcnt vmcnt(0)" ::: "memory");
    __builtin_amdgcn_s_barrier();
    bf16x8 qf[4];
#pragma unroll
    for (int s = 0; s < 4; s++)
        qf[s] = *reinterpret_cast<const bf16x8*>(
            lds + wsel * 8192 + ((w & 3) * 32 + l31) * 64 + ((2 * s + hi) ^ sx) * 8);
    asm volatile("s_waitcnt lgkmcnt(0)" ::: "memory");
    __builtin_amdgcn_sched_barrier(0);
    __builtin_amdgcn_s_barrier();

    const int srow = tid >> 3;
    const int schs = (tid & 7) ^ (srow & 7);
    const unsigned short* ksrc0 = kp + ((size_t)b * T_SZ + srow) * C_SZ + h * D_SZ + schs * 8;
    const unsigned short* vsrc0 = vtp + (size_t)bh * 64 * T_SZ + (size_t)srow * T_SZ + schs * 8;
#define STAGE(KV0, BI)                                                        \
    do {                                                                      \
        async16(ksrc0 + (size_t)(KV0) * C_SZ, lds + (BI) * 8192 + tid * 8);   \
        async16(vsrc0 + (KV0), lds + (BI) * 8192 + 4096 + tid * 8);           \
    } while (0)

    f32x16 accO[2];
    accO[0] = zero16();
    accO[1] = zero16();
    float lsum = 0.f;

    STAGE(0, 0);
    const int nkv = 32 - 2 * pr; // = 2*qtB + 2, uniform per block
    for (int kv = 0; kv < nkv; kv++) {
        const int cur = kv & 1;
        const int kv0 = kv * 64;
        if (kv + 1 < nkv) {
            STAGE(kv0 + 64, cur ^ 1);
            asm volatile("s_waitcnt vmcnt(2)" ::: "memory");
        } else {
            asm volatile("s_waitcnt vmcnt(0)" ::: "memory");
        }
        __builtin_amdgcn_s_barrier();
        asm volatile("" ::: "memory");

        if (kv0 <= wq0 + 31) { // wave-uniform guard
            const unsigned short* Kb = lds + cur * 8192;
            const unsigned short* Vb = lds + cur * 8192 + 4096;
            const bool diag = (kv0 + 63) > wq0;
            __builtin_amdgcn_s_setprio(1);
#pragma unroll
            for (int kk = 0; kk < 2; kk++) {
                f32x16 sc = zero16();
                const unsigned short* krow = Kb + (kk * 32 + l31) * 64;
#pragma unroll
                for (int s = 0; s < 4; s++) {
                    bf16x8 kf = *reinterpret_cast<const bf16x8*>(krow + ((2 * s + hi) ^ sx) * 8);
                    sc = mfma32(kf, qf[s], sc);
                }
                const int kvkk = kv0 + kk * 32 + 4 * hi;
                unsigned int wd[4][2];
#pragma unroll
                for (int i = 0; i < 16; i += 2) {
                    float p0 = __builtin_amdgcn_exp2f(sc[i]);
                    float p1 = __builtin_amdgcn_exp2f(sc[i + 1]);
                    if (diag) {
                        int kg = kvkk + (i & 3) + 8 * (i >> 2);
                        p0 = (kg > qg) ? 0.f : p0;
                        p1 = (kg + 1 > qg) ? 0.f : p1;
                    }
                    lsum += p0 + p1;
                    unsigned int wv;
                    asm("v_cvt_pk_bf16_f32 %0, %1, %2" : "=v"(wv) : "v"(p0), "v"(p1));
                    wd[i >> 2][(i >> 1) & 1] = wv;
                }
#pragma unroll
                for (int s = 0; s < 2; s++) {
                    uivec2 r0 = __builtin_amdgcn_permlane32_swap(wd[2 * s][0], wd[2 * s + 1][0],
                                                                 false, false);
                    uivec2 r1 = __builtin_amdgcn_permlane32_swap(wd[2 * s][1], wd[2 * s + 1][1],
                                                                 false, false);
                    uivec4 frv = {r0.x, r1.x, r0.y, r1.y};
                    bf16x8 pfrag = __builtin_bit_cast(bf16x8, frv);
                    const int ks = kk * 2 + s;
#pragma unroll
                    for (int dt = 0; dt < 2; dt++) {
                        bf16x8 vf = *reinterpret_cast<const bf16x8*>(
                            Vb + (dt * 32 + l31) * 64 + ((2 * ks + hi) ^ sx) * 8);
                        accO[dt] = mfma32(vf, pfrag, accO[dt]);
                    }
                }
            }
            __builtin_amdgcn_s_setprio(0);
        }
        asm volatile("" ::: "memory");
        __builtin_amdgcn_s_barrier();
    }
#undef STAGE

    __syncthreads();
    float lt = lsum + __shfl_xor(lsum, 32, 64);
    float linv = 1.0f / lt;
    unsigned int* ow = (unsigned int*)lds + w * 1024;
#pragma unroll
    for (int dt = 0; dt < 2; dt++) {
#pragma unroll
        for (int i = 0; i < 16; i += 2) {
            float v0 = accO[dt][i] * linv;
            float v1 = accO[dt][i + 1] * linv;
            unsigned int wv;
            asm("v_cvt_pk_bf16_f32 %0, %1, %2" : "=v"(wv) : "v"(v0), "v"(v1));
            int idx = ((i & 3) + 8 * (i >> 2) + 4 * hi + 32 * dt) >> 1;
            ow[l31 * 32 + (idx ^ (sx << 2))] = wv;
        }
    }
    int q2 = lane >> 1;
    int c0 = (lane & 1) * 4;
    unsigned short* orow = attn_out + (size_t)(b * T_SZ + wq0 + q2) * C_SZ + h * D_SZ;
#pragma unroll
    for (int j = 0; j < 4; j++) {
        int c = c0 + j;
        uint4 val = *(const uint4*)(ow + q2 * 32 + ((c ^ (q2 & 7)) * 4));
        *(uint4*)(orow + c * 8) = val;
    }
}

extern "C" void kernel_launch(void* const* d_in, const int* in_sizes, int n_in,
                              void* d_out, int out_size, void* d_ws, size_t ws_size,
                              hipStream_t stream) {
    (void)in_sizes; (void)n_in; (void)out_size;
    const float* x     = (const float*)d_in[0];
    const float* w_qkv = (const float*)d_in[1];
    const float* b_qkv = (const float*)d_in[2];
    const float* w_out = (const float*)d_in[3];
    const float* b_out = (const float*)d_in[4];
    float* out = (float*)d_out;

    unsigned short* xb    = (unsigned short*)d_ws;            // M x C
    unsigned short* wqkvT = xb + (size_t)M_SZ * C_SZ;         // N3 x C
    unsigned short* woutT = wqkvT + (size_t)N3_SZ * C_SZ;     // C x C
    unsigned short* qp    = woutT + (size_t)C_SZ * C_SZ;      // M x C (Q plane)
    unsigned short* kpp   = qp + (size_t)M_SZ * C_SZ;         // M x C (K plane)
    unsigned short* vtp   = kpp + (size_t)M_SZ * C_SZ;        // BH x 64 x T (Vt plane)
    unsigned short* attn  = vtp + (size_t)M_SZ * C_SZ;        // M x C
    float* rtab = (float*)(attn + (size_t)M_SZ * C_SZ);       // T x 64 (cos/sin interleaved)
    size_t needed = (size_t)((char*)(rtab + T_SZ * 64) - (char*)d_ws);
    if (ws_size < needed) return;

    hipFuncSetAttribute((const void*)k_gemmqkv,
                        hipFuncAttributeMaxDynamicSharedMemorySize, 49152);
    hipFuncSetAttribute((const void*)k_gemmout,
                        hipFuncAttributeMaxDynamicSharedMemorySize, 49152);

    k_prologue<<<2048 + 3072 + 1024 + 256, 256, 0, stream>>>(
        (const float4*)x, (uint2*)xb, w_qkv, wqkvT, w_out, woutT, rtab);
    k_gemmqkv<<<dim3(12, 64), 512, 49152, stream>>>(xb, wqkvT, b_qkv, qp, kpp, vtp, rtab);
    k_attn<<<dim3(8, 64), 512, 0, stream>>>(qp, kpp, vtp, attn);
    k_gemmout<<<dim3(4, 64), 512, 49152, stream>>>(attn, woutT, b_out, out);
}

// Round 15
// 156.795 us; speedup vs baseline: 1.0575x; 1.0575x over previous
//
#include <hip/hip_runtime.h>
#include <stdint.h>

#define B_SZ 4
#define T_SZ 2048
#define H_SZ 16
#define D_SZ 64
#define C_SZ 1024
#define N3_SZ 3072
#define M_SZ (B_SZ * T_SZ) // 8192

using bf16x8 = __attribute__((ext_vector_type(8))) __bf16;
using f32x4  = __attribute__((ext_vector_type(4))) float;
using f32x16 = __attribute__((ext_vector_type(16))) float;
using uivec2 = __attribute__((ext_vector_type(2))) unsigned int;
using uivec4 = __attribute__((ext_vector_type(4))) unsigned int;

__device__ __forceinline__ unsigned short f2bf(float f) {
    union { float f; unsigned int u; } v; v.f = f;
    unsigned int r = v.u + 0x7FFFu + ((v.u >> 16) & 1u);
    return (unsigned short)(r >> 16);
}
__device__ __forceinline__ unsigned int pack_bf2(float lo, float hi) {
    return (unsigned int)f2bf(lo) | ((unsigned int)f2bf(hi) << 16);
}

__device__ __forceinline__ void async16(const void* g, void* l) {
    __builtin_amdgcn_global_load_lds((const __attribute__((address_space(1))) void*)g,
                                     (__attribute__((address_space(3))) void*)l, 16, 0, 0);
}
__device__ __forceinline__ f32x4 mfma16(bf16x8 a, bf16x8 b, f32x4 c) {
    return __builtin_amdgcn_mfma_f32_16x16x32_bf16(a, b, c, 0, 0, 0);
}
__device__ __forceinline__ f32x16 mfma32(bf16x8 a, bf16x8 b, f32x16 c) {
    return __builtin_amdgcn_mfma_f32_32x32x16_bf16(a, b, c, 0, 0, 0);
}
__device__ __forceinline__ f32x16 zero16() {
    f32x16 z;
#pragma unroll
    for (int i = 0; i < 16; i++) z[i] = 0.f;
    return z;
}

// ---------------- fused prologue: x->bf16, both weight transposes, rope table ----------
__global__ __launch_bounds__(256) void k_prologue(const float4* __restrict__ x,
                                                  uint2* __restrict__ xb,
                                                  const float* __restrict__ w_qkv,
                                                  unsigned short* __restrict__ wqkvT,
                                                  const float* __restrict__ w_out,
                                                  unsigned short* __restrict__ woutT,
                                                  float* __restrict__ rtab) {
    __shared__ float tile[32][33];
    const int bid = blockIdx.x;
    const int tid = threadIdx.x;
    if (bid < 2048) {
        const int n4 = M_SZ * C_SZ / 4;
        for (int i = bid * 256 + tid; i < n4; i += 2048 * 256) {
            float4 v = x[i];
            uint2 o;
            o.x = pack_bf2(v.x, v.y);
            o.y = pack_bf2(v.z, v.w);
            xb[i] = o;
        }
    } else if (bid < 2048 + 3072) {
        const int t = bid - 2048;
        const int n0 = (t % (N3_SZ / 32)) * 32, k0 = (t / (N3_SZ / 32)) * 32;
        const int tx = tid & 31, ty = tid >> 5;
#pragma unroll
        for (int j = 0; j < 32; j += 8)
            tile[ty + j][tx] = w_qkv[(size_t)(k0 + ty + j) * N3_SZ + (n0 + tx)];
        __syncthreads();
#pragma unroll
        for (int j = 0; j < 32; j += 8)
            wqkvT[(size_t)(n0 + ty + j) * C_SZ + (k0 + tx)] = f2bf(tile[tx][ty + j]);
    } else if (bid < 2048 + 3072 + 1024) {
        const int t = bid - (2048 + 3072);
        const int n0 = (t % (C_SZ / 32)) * 32, k0 = (t / (C_SZ / 32)) * 32;
        const int tx = tid & 31, ty = tid >> 5;
#pragma unroll
        for (int j = 0; j < 32; j += 8)
            tile[ty + j][tx] = w_out[(size_t)(k0 + ty + j) * C_SZ + (n0 + tx)];
        __syncthreads();
#pragma unroll
        for (int j = 0; j < 32; j += 8)
            woutT[(size_t)(n0 + ty + j) * C_SZ + (k0 + tx)] = f2bf(tile[tx][ty + j]);
    } else {
        const int i = (bid - (2048 + 3072 + 1024)) * 256 + tid;
        if (i < T_SZ * 32) {
            int t = i >> 5, fq = i & 31;
            float invf = powf(10000.0f, -(float)fq / 32.0f);
            float ang = (float)t * invf;
            rtab[t * 64 + fq * 2]     = cosf(ang);
            rtab[t * 64 + fq * 2 + 1] = sinf(ang);
        }
    }
}

// ==== GEMM body: 128x256, BK=32, TRIPLE-buffer 72KB -> 2 blocks/CU, 1 barrier/tile ====
// R13 structure. Change vs R13: NO lgkmcnt(0)/sched_barrier fence before the MFMA
// cluster — fragment loads are plain IR loads, so the compiler emits fine-grained
// lgkmcnt(N) and can overlap ds_reads with early MFMAs (m97 behavior). The "memory"
// clobber on the vmcnt asm before each s_barrier still pins all LDS reads inside
// their tile (no cross-barrier hoisting).
#define GEMM_BODY(Kdim)                                                                    \
    const int tid = threadIdx.x;                                                           \
    const int wave = tid >> 6, lane = tid & 63;                                            \
    const int lcol = lane & 15, lrow = lane >> 4;                                          \
    const int wm = wave >> 2, wn = wave & 3;                                               \
    const int Kd_ = (Kdim);                                                                \
    const int srow = tid >> 2;                                                             \
    const int schs = (tid & 3) ^ ((tid >> 3) & 3);                                         \
    const unsigned short* Asrc = A + (size_t)(m0 + srow) * Kd_ + schs * 8;                 \
    const unsigned short* Bsrc = BT + (size_t)(n0 + srow) * Kd_ + schs * 8;                \
    const int swz = (lrow ^ ((lcol >> 1) & 3)) * 8;                                        \
    f32x4 acc[4][4];                                                                       \
    _Pragma("unroll") for (int i = 0; i < 4; i++)                                          \
        _Pragma("unroll") for (int j = 0; j < 4; j++) acc[i][j] = (f32x4){0.f,0.f,0.f,0.f};\
    SU_B(0, 0, 0); SU_B(0, 1, 0); SU_A(0, 0);                                              \
    SU_B(1, 0, 32); SU_B(1, 1, 32); SU_A(1, 32);                                           \
    asm volatile("s_waitcnt vmcnt(3)" ::: "memory");                                       \
    __builtin_amdgcn_s_barrier();                                                          \
    const int NT = Kd_ >> 5;                                                               \
    for (int t = 0; t < NT; ++t) {                                                         \
        const int cur = t % 3;                                                             \
        int nx2 = cur + 2; if (nx2 >= 3) nx2 -= 3;                                         \
        const unsigned short* Acur = As + cur * 4096;                                      \
        const unsigned short* Bcur = Bs + cur * 8192;                                      \
        const size_t kn = (size_t)(t + 2) * 32;                                            \
        const bool more2 = (t + 2 < NT);                                                   \
        bf16x8 a0 = LD_A(0), a1 = LD_A(1), a2 = LD_A(2), a3 = LD_A(3);                     \
        bf16x8 b0 = LD_B(0), b1 = LD_B(1), b2 = LD_B(2), b3 = LD_B(3);                     \
        if (more2) { SU_B(nx2, 0, kn); SU_B(nx2, 1, kn); SU_A(nx2, kn); }                  \
        __builtin_amdgcn_s_setprio(1);                                                     \
        acc[0][0] = mfma16(a0, b0, acc[0][0]);                                             \
        acc[0][1] = mfma16(a0, b1, acc[0][1]);                                             \
        acc[0][2] = mfma16(a0, b2, acc[0][2]);                                             \
        acc[0][3] = mfma16(a0, b3, acc[0][3]);                                             \
        acc[1][0] = mfma16(a1, b0, acc[1][0]);                                             \
        acc[1][1] = mfma16(a1, b1, acc[1][1]);                                             \
        acc[1][2] = mfma16(a1, b2, acc[1][2]);                                             \
        acc[1][3] = mfma16(a1, b3, acc[1][3]);                                             \
        acc[2][0] = mfma16(a2, b0, acc[2][0]);                                             \
        acc[2][1] = mfma16(a2, b1, acc[2][1]);                                             \
        acc[2][2] = mfma16(a2, b2, acc[2][2]);                                             \
        acc[2][3] = mfma16(a2, b3, acc[2][3]);                                             \
        acc[3][0] = mfma16(a3, b0, acc[3][0]);                                             \
        acc[3][1] = mfma16(a3, b1, acc[3][1]);                                             \
        acc[3][2] = mfma16(a3, b2, acc[3][2]);                                             \
        acc[3][3] = mfma16(a3, b3, acc[3][3]);                                             \
        __builtin_amdgcn_s_setprio(0);                                                     \
        if (more2) asm volatile("s_waitcnt vmcnt(3)" ::: "memory");                        \
        else       asm volatile("s_waitcnt vmcnt(0)" ::: "memory");                        \
        __builtin_amdgcn_s_barrier();                                                      \
    }

// As: [3][128*32] (8KB each); Bs: [3][256*32] (16KB each, unit q = 128 rows)
#define SU_A(BI, KO) async16(Asrc + (KO), As + (BI) * 4096 + tid * 8)
#define SU_B(BI, Q, KO) async16(Bsrc + (size_t)(Q) * 128 * Kd_ + (KO), \
                                Bs + (BI) * 8192 + (Q) * 4096 + tid * 8)
#define LD_A(MF) (*reinterpret_cast<const bf16x8*>( \
    Acur + (wm * 64 + (MF) * 16 + lcol) * 32 + swz))
#define LD_B(NF) (*reinterpret_cast<const bf16x8*>( \
    Bcur + (wn * 64 + (NF) * 16 + lcol) * 32 + swz))

// ---------------- QKV GEMM: fused RoPE epilogue; Q/K planes + direct-transposed V -------
__global__ __launch_bounds__(512, 2) void k_gemmqkv(const unsigned short* __restrict__ A,
                                                    const unsigned short* __restrict__ BT,
                                                    const float* __restrict__ bias,
                                                    unsigned short* __restrict__ qp,
                                                    unsigned short* __restrict__ kp,
                                                    unsigned short* __restrict__ vtp,
                                                    const float* __restrict__ rtab) {
    extern __shared__ unsigned short lds[];
    unsigned short* As = lds;               // [3][128*32]
    unsigned short* Bs = lds + 3 * 4096;    // [3][256*32]
    int orig = blockIdx.x + gridDim.x * blockIdx.y; // 0..767
    int lin = (orig & 7) * 96 + (orig >> 3);
    const int n0 = (lin % 12) * 256, m0 = (lin / 12) * 128;
    GEMM_BODY(C_SZ)

    const int cb = n0 + wn * 64; // wave col span == one head
    float bv[4];
#pragma unroll
    for (int nf = 0; nf < 4; nf++) bv[nf] = bias[cb + nf * 16 + lcol];
    if (cb < 2 * C_SZ) {
        const float scl = (cb < C_SZ) ? 0.125f * 1.4426950408889634f : 1.0f;
        unsigned short* dst = (cb < C_SZ) ? qp : kp;
        const int cbl = cb & (C_SZ - 1);
#pragma unroll
        for (int mf = 0; mf < 4; mf++) {
#pragma unroll
            for (int r = 0; r < 4; r++) {
                int row = m0 + wm * 64 + mf * 16 + lrow * 4 + r;
                int t = row & (T_SZ - 1);
#pragma unroll
                for (int p = 0; p < 2; p++) {
                    int fq = p * 16 + lcol;
                    float2 cs = *(const float2*)(rtab + t * 64 + fq * 2);
                    float a  = acc[mf][p][r]     + bv[p];
                    float bb = acc[mf][p + 2][r] + bv[p + 2];
                    float lo = (a * cs.x - bb * cs.y) * scl;
                    float hi = (bb * cs.x + a * cs.y) * scl;
                    dst[(size_t)row * C_SZ + cbl + fq]      = f2bf(lo);
                    dst[(size_t)row * C_SZ + cbl + fq + 32] = f2bf(hi);
                }
            }
        }
    } else {
        // V: direct transposed store to vtp[bh][d][t]
        const int hh = (cb - 2 * C_SZ) >> 6;
        const int bb = m0 >> 11;
        const int bhv = bb * H_SZ + hh;
        const int t0w = (m0 & (T_SZ - 1)) + wm * 64;
#pragma unroll
        for (int nf = 0; nf < 4; nf++) {
            const int d = nf * 16 + lcol;
            unsigned short* vrow = vtp + ((size_t)bhv * 64 + d) * T_SZ + t0w;
#pragma unroll
            for (int mf = 0; mf < 4; mf++) {
                int t = mf * 16 + lrow * 4;
                uint2 o;
                o.x = pack_bf2(acc[mf][nf][0] + bv[nf], acc[mf][nf][1] + bv[nf]);
                o.y = pack_bf2(acc[mf][nf][2] + bv[nf], acc[mf][nf][3] + bv[nf]);
                *(uint2*)(vrow + t) = o;
            }
        }
    }
}

// ---------------- out-proj GEMM: 128x256, f32 + bias epilogue ----------------
__global__ __launch_bounds__(512, 2) void k_gemmout(const unsigned short* __restrict__ A,
                                                    const unsigned short* __restrict__ BT,
                                                    const float* __restrict__ bias,
                                                    float* __restrict__ Cout) {
    extern __shared__ unsigned short lds[];
    unsigned short* As = lds;
    unsigned short* Bs = lds + 3 * 4096;
    int orig = blockIdx.x + gridDim.x * blockIdx.y; // 0..255
    int lin = (orig & 7) * 32 + (orig >> 3);
    const int n0 = (lin % 4) * 256, m0 = (lin / 4) * 128;
    GEMM_BODY(C_SZ)
    const int cb = n0 + wn * 64;
#pragma unroll
    for (int nf = 0; nf < 4; nf++) {
        int col = cb + nf * 16 + lcol;
        float bv = bias[col];
#pragma unroll
        for (int mf = 0; mf < 4; mf++) {
#pragma unroll
            for (int r = 0; r < 4; r++) {
                int row = m0 + wm * 64 + mf * 16 + lrow * 4 + r;
                Cout[(size_t)row * C_SZ + col] = acc[mf][nf][r] + bv;
            }
        }
    }
}

#undef SU_A
#undef SU_B
#undef LD_A
#undef LD_B

// ---------------- causal flash attention (v5r: paired q-tiles, 8 waves, 32KB LDS) -------
__global__ __launch_bounds__(512, 4) void k_attn(const unsigned short* __restrict__ qp,
                                                 const unsigned short* __restrict__ kp,
                                                 const unsigned short* __restrict__ vtp,
                                                 unsigned short* __restrict__ attn_out) {
    __shared__ __align__(16) unsigned short lds[16384]; // [K0|V0|K1|V1] 4x8KB; Q overlay
    int orig = blockIdx.x + gridDim.x * blockIdx.y;     // grid (8,64) = 512
    int lin = (orig & 7) * 64 + (orig >> 3);            // 8 bh per XCD
    const int pr = lin & 7, bh = lin >> 3;
    const int b = bh >> 4, h = bh & 15;
    const int qtA = pr, qtB = 15 - pr;
    const int tid = threadIdx.x;
    const int w = tid >> 6, lane = tid & 63;
    const int l31 = lane & 31, hi = lane >> 5;
    const int sx = l31 & 7;
    const int wsel = w >> 2;
    const int wq0 = (wsel ? qtB : qtA) * 128 + (w & 3) * 32;
    const int qg = wq0 + l31;

#pragma unroll
    for (int L = 0; L < 4; L++) {
        int flat = L * 512 + tid;
        int row = flat >> 3, ch = flat & 7;
        int qrow = (row < 128) ? (qtA * 128 + row) : (qtB * 128 + row - 128);
        int chs = ch ^ (row & 7);
        async16(qp + ((size_t)(b * T_SZ + qrow)) * C_SZ + h * D_SZ + chs * 8, lds + flat * 8);
    }
    asm volatile("s_waitcnt vmcnt(0)" ::: "memory");
    __builtin_amdgcn_s_barrier();
    bf16x8 qf[4];
#pragma unroll
    for (int s = 0; s < 4; s++)
        qf[s] = *reinterpret_cast<const bf16x8*>(
            lds + wsel * 8192 + ((w & 3) * 32 + l31) * 64 + ((2 * s + hi) ^ sx) * 8);
    asm volatile("s_waitcnt lgkmcnt(0)" ::: "memory");
    __builtin_amdgcn_sched_barrier(0);
    __builtin_amdgcn_s_barrier();

    const int srow = tid >> 3;
    const int schs = (tid & 7) ^ (srow & 7);
    const unsigned short* ksrc0 = kp + ((size_t)b * T_SZ + srow) * C_SZ + h * D_SZ + schs * 8;
    const unsigned short* vsrc0 = vtp + (size_t)bh * 64 * T_SZ + (size_t)srow * T_SZ + schs * 8;
#define STAGE(KV0, BI)                                                        \
    do {                                                                      \
        async16(ksrc0 + (size_t)(KV0) * C_SZ, lds + (BI) * 8192 + tid * 8);   \
        async16(vsrc0 + (KV0), lds + (BI) * 8192 + 4096 + tid * 8);           \
    } while (0)

    f32x16 accO[2];
    accO[0] = zero16();
    accO[1] = zero16();
    float lsum = 0.f;

    STAGE(0, 0);
    const int nkv = 32 - 2 * pr; // = 2*qtB + 2, uniform per block
    for (int kv = 0; kv < nkv; kv++) {
        const int cur = kv & 1;
        const int kv0 = kv * 64;
        if (kv + 1 < nkv) {
            STAGE(kv0 + 64, cur ^ 1);
            asm volatile("s_waitcnt vmcnt(2)" ::: "memory");
        } else {
            asm volatile("s_waitcnt vmcnt(0)" ::: "memory");
        }
        __builtin_amdgcn_s_barrier();
        asm volatile("" ::: "memory");

        if (kv0 <= wq0 + 31) { // wave-uniform guard
            const unsigned short* Kb = lds + cur * 8192;
            const unsigned short* Vb = lds + cur * 8192 + 4096;
            const bool diag = (kv0 + 63) > wq0;
            __builtin_amdgcn_s_setprio(1);
#pragma unroll
            for (int kk = 0; kk < 2; kk++) {
                f32x16 sc = zero16();
                const unsigned short* krow = Kb + (kk * 32 + l31) * 64;
#pragma unroll
                for (int s = 0; s < 4; s++) {
                    bf16x8 kf = *reinterpret_cast<const bf16x8*>(krow + ((2 * s + hi) ^ sx) * 8);
                    sc = mfma32(kf, qf[s], sc);
                }
                const int kvkk = kv0 + kk * 32 + 4 * hi;
                unsigned int wd[4][2];
#pragma unroll
                for (int i = 0; i < 16; i += 2) {
                    float p0 = __builtin_amdgcn_exp2f(sc[i]);
                    float p1 = __builtin_amdgcn_exp2f(sc[i + 1]);
                    if (diag) {
                        int kg = kvkk + (i & 3) + 8 * (i >> 2);
                        p0 = (kg > qg) ? 0.f : p0;
                        p1 = (kg + 1 > qg) ? 0.f : p1;
                    }
                    lsum += p0 + p1;
                    unsigned int wv;
                    asm("v_cvt_pk_bf16_f32 %0, %1, %2" : "=v"(wv) : "v"(p0), "v"(p1));
                    wd[i >> 2][(i >> 1) & 1] = wv;
                }
#pragma unroll
                for (int s = 0; s < 2; s++) {
                    uivec2 r0 = __builtin_amdgcn_permlane32_swap(wd[2 * s][0], wd[2 * s + 1][0],
                                                                 false, false);
                    uivec2 r1 = __builtin_amdgcn_permlane32_swap(wd[2 * s][1], wd[2 * s + 1][1],
                                                                 false, false);
                    uivec4 frv = {r0.x, r1.x, r0.y, r1.y};
                    bf16x8 pfrag = __builtin_bit_cast(bf16x8, frv);
                    const int ks = kk * 2 + s;
#pragma unroll
                    for (int dt = 0; dt < 2; dt++) {
                        bf16x8 vf = *reinterpret_cast<const bf16x8*>(
                            Vb + (dt * 32 + l31) * 64 + ((2 * ks + hi) ^ sx) * 8);
                        accO[dt] = mfma32(vf, pfrag, accO[dt]);
                    }
                }
            }
            __builtin_amdgcn_s_setprio(0);
        }
        asm volatile("" ::: "memory");
        __builtin_amdgcn_s_barrier();
    }
#undef STAGE

    __syncthreads();
    float lt = lsum + __shfl_xor(lsum, 32, 64);
    float linv = 1.0f / lt;
    unsigned int* ow = (unsigned int*)lds + w * 1024;
#pragma unroll
    for (int dt = 0; dt < 2; dt++) {
#pragma unroll
        for (int i = 0; i < 16; i += 2) {
            float v0 = accO[dt][i] * linv;
            float v1 = accO[dt][i + 1] * linv;
            unsigned int wv;
            asm("v_cvt_pk_bf16_f32 %0, %1, %2" : "=v"(wv) : "v"(v0), "v"(v1));
            int idx = ((i & 3) + 8 * (i >> 2) + 4 * hi + 32 * dt) >> 1;
            ow[l31 * 32 + (idx ^ (sx << 2))] = wv;
        }
    }
    int q2 = lane >> 1;
    int c0 = (lane & 1) * 4;
    unsigned short* orow = attn_out + (size_t)(b * T_SZ + wq0 + q2) * C_SZ + h * D_SZ;
#pragma unroll
    for (int j = 0; j < 4; j++) {
        int c = c0 + j;
        uint4 val = *(const uint4*)(ow + q2 * 32 + ((c ^ (q2 & 7)) * 4));
        *(uint4*)(orow + c * 8) = val;
    }
}

extern "C" void kernel_launch(void* const* d_in, const int* in_sizes, int n_in,
                              void* d_out, int out_size, void* d_ws, size_t ws_size,
                              hipStream_t stream) {
    (void)in_sizes; (void)n_in; (void)out_size;
    const float* x     = (const float*)d_in[0];
    const float* w_qkv = (const float*)d_in[1];
    const float* b_qkv = (const float*)d_in[2];
    const float* w_out = (const float*)d_in[3];
    const float* b_out = (const float*)d_in[4];
    float* out = (float*)d_out;

    unsigned short* xb    = (unsigned short*)d_ws;            // M x C
    unsigned short* wqkvT = xb + (size_t)M_SZ * C_SZ;         // N3 x C
    unsigned short* woutT = wqkvT + (size_t)N3_SZ * C_SZ;     // C x C
    unsigned short* qp    = woutT + (size_t)C_SZ * C_SZ;      // M x C (Q plane)
    unsigned short* kpp   = qp + (size_t)M_SZ * C_SZ;         // M x C (K plane)
    unsigned short* vtp   = kpp + (size_t)M_SZ * C_SZ;        // BH x 64 x T (Vt plane)
    unsigned short* attn  = vtp + (size_t)M_SZ * C_SZ;        // M x C
    float* rtab = (float*)(attn + (size_t)M_SZ * C_SZ);       // T x 64 (cos/sin interleaved)
    size_t needed = (size_t)((char*)(rtab + T_SZ * 64) - (char*)d_ws);
    if (ws_size < needed) return;

    hipFuncSetAttribute((const void*)k_gemmqkv,
                        hipFuncAttributeMaxDynamicSharedMemorySize, 73728);
    hipFuncSetAttribute((const void*)k_gemmout,
                        hipFuncAttributeMaxDynamicSharedMemorySize, 73728);

    k_prologue<<<2048 + 3072 + 1024 + 256, 256, 0, stream>>>(
        (const float4*)x, (uint2*)xb, w_qkv, wqkvT, w_out, woutT, rtab);
    k_gemmqkv<<<dim3(12, 64), 512, 73728, stream>>>(xb, wqkvT, b_qkv, qp, kpp, vtp, rtab);
    k_attn<<<dim3(8, 64), 512, 0, stream>>>(qp, kpp, vtp, attn);
    k_gemmout<<<dim3(4, 64), 512, 73728, stream>>>(attn, woutT, b_out, out);
}

// Round 16
// 156.429 us; speedup vs baseline: 1.0600x; 1.0023x over previous
//
#include <hip/hip_runtime.h>
#include <stdint.h>

#define B_SZ 4
#define T_SZ 2048
#define H_SZ 16
#define D_SZ 64
#define C_SZ 1024
#define N3_SZ 3072
#define M_SZ (B_SZ * T_SZ) // 8192

using bf16x8 = __attribute__((ext_vector_type(8))) __bf16;
using f32x4  = __attribute__((ext_vector_type(4))) float;
using f32x16 = __attribute__((ext_vector_type(16))) float;
using uivec2 = __attribute__((ext_vector_type(2))) unsigned int;
using uivec4 = __attribute__((ext_vector_type(4))) unsigned int;

__device__ __forceinline__ unsigned short f2bf(float f) {
    union { float f; unsigned int u; } v; v.f = f;
    unsigned int r = v.u + 0x7FFFu + ((v.u >> 16) & 1u);
    return (unsigned short)(r >> 16);
}
__device__ __forceinline__ unsigned int pack_bf2(float lo, float hi) {
    return (unsigned int)f2bf(lo) | ((unsigned int)f2bf(hi) << 16);
}

__device__ __forceinline__ void async16(const void* g, void* l) {
    __builtin_amdgcn_global_load_lds((const __attribute__((address_space(1))) void*)g,
                                     (__attribute__((address_space(3))) void*)l, 16, 0, 0);
}
__device__ __forceinline__ f32x4 mfma16(bf16x8 a, bf16x8 b, f32x4 c) {
    return __builtin_amdgcn_mfma_f32_16x16x32_bf16(a, b, c, 0, 0, 0);
}
__device__ __forceinline__ f32x16 mfma32(bf16x8 a, bf16x8 b, f32x16 c) {
    return __builtin_amdgcn_mfma_f32_32x32x16_bf16(a, b, c, 0, 0, 0);
}
__device__ __forceinline__ f32x16 zero16() {
    f32x16 z;
#pragma unroll
    for (int i = 0; i < 16; i++) z[i] = 0.f;
    return z;
}

// ---------------- fused prologue: x->bf16, both weight transposes, rope table ----------
__global__ __launch_bounds__(256) void k_prologue(const float4* __restrict__ x,
                                                  uint2* __restrict__ xb,
                                                  const float* __restrict__ w_qkv,
                                                  unsigned short* __restrict__ wqkvT,
                                                  const float* __restrict__ w_out,
                                                  unsigned short* __restrict__ woutT,
                                                  float* __restrict__ rtab) {
    __shared__ float tile[32][33];
    const int bid = blockIdx.x;
    const int tid = threadIdx.x;
    if (bid < 2048) {
        const int n4 = M_SZ * C_SZ / 4;
        for (int i = bid * 256 + tid; i < n4; i += 2048 * 256) {
            float4 v = x[i];
            uint2 o;
            o.x = pack_bf2(v.x, v.y);
            o.y = pack_bf2(v.z, v.w);
            xb[i] = o;
        }
    } else if (bid < 2048 + 3072) {
        const int t = bid - 2048;
        const int n0 = (t % (N3_SZ / 32)) * 32, k0 = (t / (N3_SZ / 32)) * 32;
        const int tx = tid & 31, ty = tid >> 5;
#pragma unroll
        for (int j = 0; j < 32; j += 8)
            tile[ty + j][tx] = w_qkv[(size_t)(k0 + ty + j) * N3_SZ + (n0 + tx)];
        __syncthreads();
#pragma unroll
        for (int j = 0; j < 32; j += 8)
            wqkvT[(size_t)(n0 + ty + j) * C_SZ + (k0 + tx)] = f2bf(tile[tx][ty + j]);
    } else if (bid < 2048 + 3072 + 1024) {
        const int t = bid - (2048 + 3072);
        const int n0 = (t % (C_SZ / 32)) * 32, k0 = (t / (C_SZ / 32)) * 32;
        const int tx = tid & 31, ty = tid >> 5;
#pragma unroll
        for (int j = 0; j < 32; j += 8)
            tile[ty + j][tx] = w_out[(size_t)(k0 + ty + j) * C_SZ + (n0 + tx)];
        __syncthreads();
#pragma unroll
        for (int j = 0; j < 32; j += 8)
            woutT[(size_t)(n0 + ty + j) * C_SZ + (k0 + tx)] = f2bf(tile[tx][ty + j]);
    } else {
        const int i = (bid - (2048 + 3072 + 1024)) * 256 + tid;
        if (i < T_SZ * 32) {
            int t = i >> 5, fq = i & 31;
            float invf = powf(10000.0f, -(float)fq / 32.0f);
            float ang = (float)t * invf;
            rtab[t * 64 + fq * 2]     = cosf(ang);
            rtab[t * 64 + fq * 2 + 1] = sinf(ang);
        }
    }
}

// ==== GEMM body: 128x256, BK=32, TRIPLE-buffer 72KB -> 2 blocks/CU, 1 barrier/tile ====
// Measured sweet spot (R13/R15): BK=64 -> 1 block/CU (R11, 67us); dbuf+drain at 3/CU
// loses to counted-vmcnt (R14, 70.6us); smaller BN amplifies LDS traffic. Stage tile
// t+2 (3 units) at tile t; vmcnt(3) at tile end waits t+1's units (2-tile slack).
#define GEMM_BODY(Kdim)                                                                    \
    const int tid = threadIdx.x;                                                           \
    const int wave = tid >> 6, lane = tid & 63;                                            \
    const int lcol = lane & 15, lrow = lane >> 4;                                          \
    const int wm = wave >> 2, wn = wave & 3;                                               \
    const int Kd_ = (Kdim);                                                                \
    const int srow = tid >> 2;                                                             \
    const int schs = (tid & 3) ^ ((tid >> 3) & 3);                                         \
    const unsigned short* Asrc = A + (size_t)(m0 + srow) * Kd_ + schs * 8;                 \
    const unsigned short* Bsrc = BT + (size_t)(n0 + srow) * Kd_ + schs * 8;                \
    const int swz = (lrow ^ ((lcol >> 1) & 3)) * 8;                                        \
    f32x4 acc[4][4];                                                                       \
    _Pragma("unroll") for (int i = 0; i < 4; i++)                                          \
        _Pragma("unroll") for (int j = 0; j < 4; j++) acc[i][j] = (f32x4){0.f,0.f,0.f,0.f};\
    SU_B(0, 0, 0); SU_B(0, 1, 0); SU_A(0, 0);                                              \
    SU_B(1, 0, 32); SU_B(1, 1, 32); SU_A(1, 32);                                           \
    asm volatile("s_waitcnt vmcnt(3)" ::: "memory");                                       \
    __builtin_amdgcn_s_barrier();                                                          \
    const int NT = Kd_ >> 5;                                                               \
    for (int t = 0; t < NT; ++t) {                                                         \
        const int cur = t % 3;                                                             \
        int nx2 = cur + 2; if (nx2 >= 3) nx2 -= 3;                                         \
        const unsigned short* Acur = As + cur * 4096;                                      \
        const unsigned short* Bcur = Bs + cur * 8192;                                      \
        const size_t kn = (size_t)(t + 2) * 32;                                            \
        const bool more2 = (t + 2 < NT);                                                   \
        bf16x8 a0 = LD_A(0), a1 = LD_A(1), a2 = LD_A(2), a3 = LD_A(3);                     \
        bf16x8 b0 = LD_B(0), b1 = LD_B(1), b2 = LD_B(2), b3 = LD_B(3);                     \
        if (more2) { SU_B(nx2, 0, kn); SU_B(nx2, 1, kn); SU_A(nx2, kn); }                  \
        __builtin_amdgcn_s_setprio(1);                                                     \
        acc[0][0] = mfma16(a0, b0, acc[0][0]);                                             \
        acc[0][1] = mfma16(a0, b1, acc[0][1]);                                             \
        acc[0][2] = mfma16(a0, b2, acc[0][2]);                                             \
        acc[0][3] = mfma16(a0, b3, acc[0][3]);                                             \
        acc[1][0] = mfma16(a1, b0, acc[1][0]);                                             \
        acc[1][1] = mfma16(a1, b1, acc[1][1]);                                             \
        acc[1][2] = mfma16(a1, b2, acc[1][2]);                                             \
        acc[1][3] = mfma16(a1, b3, acc[1][3]);                                             \
        acc[2][0] = mfma16(a2, b0, acc[2][0]);                                             \
        acc[2][1] = mfma16(a2, b1, acc[2][1]);                                             \
        acc[2][2] = mfma16(a2, b2, acc[2][2]);                                             \
        acc[2][3] = mfma16(a2, b3, acc[2][3]);                                             \
        acc[3][0] = mfma16(a3, b0, acc[3][0]);                                             \
        acc[3][1] = mfma16(a3, b1, acc[3][1]);                                             \
        acc[3][2] = mfma16(a3, b2, acc[3][2]);                                             \
        acc[3][3] = mfma16(a3, b3, acc[3][3]);                                             \
        __builtin_amdgcn_s_setprio(0);                                                     \
        if (more2) asm volatile("s_waitcnt vmcnt(3)" ::: "memory");                        \
        else       asm volatile("s_waitcnt vmcnt(0)" ::: "memory");                        \
        __builtin_amdgcn_s_barrier();                                                      \
    }

// As: [3][128*32] (8KB each); Bs: [3][256*32] (16KB each, unit q = 128 rows)
#define SU_A(BI, KO) async16(Asrc + (KO), As + (BI) * 4096 + tid * 8)
#define SU_B(BI, Q, KO) async16(Bsrc + (size_t)(Q) * 128 * Kd_ + (KO), \
                                Bs + (BI) * 8192 + (Q) * 4096 + tid * 8)
#define LD_A(MF) (*reinterpret_cast<const bf16x8*>( \
    Acur + (wm * 64 + (MF) * 16 + lcol) * 32 + swz))
#define LD_B(NF) (*reinterpret_cast<const bf16x8*>( \
    Bcur + (wn * 64 + (NF) * 16 + lcol) * 32 + swz))

// ---------------- QKV GEMM: fused RoPE epilogue; Q/K planes + direct-transposed V -------
__global__ __launch_bounds__(512, 2) void k_gemmqkv(const unsigned short* __restrict__ A,
                                                    const unsigned short* __restrict__ BT,
                                                    const float* __restrict__ bias,
                                                    unsigned short* __restrict__ qp,
                                                    unsigned short* __restrict__ kp,
                                                    unsigned short* __restrict__ vtp,
                                                    const float* __restrict__ rtab) {
    extern __shared__ unsigned short lds[];
    unsigned short* As = lds;               // [3][128*32]
    unsigned short* Bs = lds + 3 * 4096;    // [3][256*32]
    int orig = blockIdx.x + gridDim.x * blockIdx.y; // 0..767
    int lin = (orig & 7) * 96 + (orig >> 3);
    const int n0 = (lin % 12) * 256, m0 = (lin / 12) * 128;
    GEMM_BODY(C_SZ)

    const int cb = n0 + wn * 64; // wave col span == one head
    float bv[4];
#pragma unroll
    for (int nf = 0; nf < 4; nf++) bv[nf] = bias[cb + nf * 16 + lcol];
    if (cb < 2 * C_SZ) {
        const float scl = (cb < C_SZ) ? 0.125f * 1.4426950408889634f : 1.0f;
        unsigned short* dst = (cb < C_SZ) ? qp : kp;
        const int cbl = cb & (C_SZ - 1);
#pragma unroll
        for (int mf = 0; mf < 4; mf++) {
#pragma unroll
            for (int r = 0; r < 4; r++) {
                int row = m0 + wm * 64 + mf * 16 + lrow * 4 + r;
                int t = row & (T_SZ - 1);
#pragma unroll
                for (int p = 0; p < 2; p++) {
                    int fq = p * 16 + lcol;
                    float2 cs = *(const float2*)(rtab + t * 64 + fq * 2);
                    float a  = acc[mf][p][r]     + bv[p];
                    float bb = acc[mf][p + 2][r] + bv[p + 2];
                    float lo = (a * cs.x - bb * cs.y) * scl;
                    float hi = (bb * cs.x + a * cs.y) * scl;
                    dst[(size_t)row * C_SZ + cbl + fq]      = f2bf(lo);
                    dst[(size_t)row * C_SZ + cbl + fq + 32] = f2bf(hi);
                }
            }
        }
    } else {
        // V: direct transposed store to vtp[bh][d][t]
        const int hh = (cb - 2 * C_SZ) >> 6;
        const int bb = m0 >> 11;
        const int bhv = bb * H_SZ + hh;
        const int t0w = (m0 & (T_SZ - 1)) + wm * 64;
#pragma unroll
        for (int nf = 0; nf < 4; nf++) {
            const int d = nf * 16 + lcol;
            unsigned short* vrow = vtp + ((size_t)bhv * 64 + d) * T_SZ + t0w;
#pragma unroll
            for (int mf = 0; mf < 4; mf++) {
                int t = mf * 16 + lrow * 4;
                uint2 o;
                o.x = pack_bf2(acc[mf][nf][0] + bv[nf], acc[mf][nf][1] + bv[nf]);
                o.y = pack_bf2(acc[mf][nf][2] + bv[nf], acc[mf][nf][3] + bv[nf]);
                *(uint2*)(vrow + t) = o;
            }
        }
    }
}

// ---------------- out-proj GEMM: 128x256, f32 + bias epilogue ----------------
__global__ __launch_bounds__(512, 2) void k_gemmout(const unsigned short* __restrict__ A,
                                                    const unsigned short* __restrict__ BT,
                                                    const float* __restrict__ bias,
                                                    float* __restrict__ Cout) {
    extern __shared__ unsigned short lds[];
    unsigned short* As = lds;
    unsigned short* Bs = lds + 3 * 4096;
    int orig = blockIdx.x + gridDim.x * blockIdx.y; // 0..255
    int lin = (orig & 7) * 32 + (orig >> 3);
    const int n0 = (lin % 4) * 256, m0 = (lin / 4) * 128;
    GEMM_BODY(C_SZ)
    const int cb = n0 + wn * 64;
#pragma unroll
    for (int nf = 0; nf < 4; nf++) {
        int col = cb + nf * 16 + lcol;
        float bv = bias[col];
#pragma unroll
        for (int mf = 0; mf < 4; mf++) {
#pragma unroll
            for (int r = 0; r < 4; r++) {
                int row = m0 + wm * 64 + mf * 16 + lrow * 4 + r;
                Cout[(size_t)row * C_SZ + col] = acc[mf][nf][r] + bv;
            }
        }
    }
}

#undef SU_A
#undef SU_B
#undef LD_A
#undef LD_B

// ---------------- causal flash attention (v5r: paired q-tiles, 8 waves, 32KB LDS) -------
// Measured best (R7/R9/R11+): single accO keeps 64-68 VGPR -> 4 blocks/CU (max waves).
// Both k-split variants (R8 spill, R10 2-blocks/CU) lost: cross-block TLP > balance.
__global__ __launch_bounds__(512, 4) void k_attn(const unsigned short* __restrict__ qp,
                                                 const unsigned short* __restrict__ kp,
                                                 const unsigned short* __restrict__ vtp,
                                                 unsigned short* __restrict__ attn_out) {
    __shared__ __align__(16) unsigned short lds[16384]; // [K0|V0|K1|V1] 4x8KB; Q overlay
    int orig = blockIdx.x + gridDim.x * blockIdx.y;     // grid (8,64) = 512
    int lin = (orig & 7) * 64 + (orig >> 3);            // 8 bh per XCD
    const int pr = lin & 7, bh = lin >> 3;
    const int b = bh >> 4, h = bh & 15;
    const int qtA = pr, qtB = 15 - pr;
    const int tid = threadIdx.x;
    const int w = tid >> 6, lane = tid & 63;
    const int l31 = lane & 31, hi = lane >> 5;
    const int sx = l31 & 7;
    const int wsel = w >> 2;
    const int wq0 = (wsel ? qtB : qtA) * 128 + (w & 3) * 32;
    const int qg = wq0 + l31;

#pragma unroll
    for (int L = 0; L < 4; L++) {
        int flat = L * 512 + tid;
        int row = flat >> 3, ch = flat & 7;
        int qrow = (row < 128) ? (qtA * 128 + row) : (qtB * 128 + row - 128);
        int chs = ch ^ (row & 7);
        async16(qp + ((size_t)(b * T_SZ + qrow)) * C_SZ + h * D_SZ + chs * 8, lds + flat * 8);
    }
    asm volatile("s_waitcnt vmcnt(0)" ::: "memory");
    __builtin_amdgcn_s_barrier();
    bf16x8 qf[4];
#pragma unroll
    for (int s = 0; s < 4; s++)
        qf[s] = *reinterpret_cast<const bf16x8*>(
            lds + wsel * 8192 + ((w & 3) * 32 + l31) * 64 + ((2 * s + hi) ^ sx) * 8);
    asm volatile("s_waitcnt lgkmcnt(0)" ::: "memory");
    __builtin_amdgcn_sched_barrier(0);
    __builtin_amdgcn_s_barrier();

    const int srow = tid >> 3;
    const int schs = (tid & 7) ^ (srow & 7);
    const unsigned short* ksrc0 = kp + ((size_t)b * T_SZ + srow) * C_SZ + h * D_SZ + schs * 8;
    const unsigned short* vsrc0 = vtp + (size_t)bh * 64 * T_SZ + (size_t)srow * T_SZ + schs * 8;
#define STAGE(KV0, BI)                                                        \
    do {                                                                      \
        async16(ksrc0 + (size_t)(KV0) * C_SZ, lds + (BI) * 8192 + tid * 8);   \
        async16(vsrc0 + (KV0), lds + (BI) * 8192 + 4096 + tid * 8);           \
    } while (0)

    f32x16 accO[2];
    accO[0] = zero16();
    accO[1] = zero16();
    float lsum = 0.f;

    STAGE(0, 0);
    const int nkv = 32 - 2 * pr; // = 2*qtB + 2, uniform per block
    for (int kv = 0; kv < nkv; kv++) {
        const int cur = kv & 1;
        const int kv0 = kv * 64;
        if (kv + 1 < nkv) {
            STAGE(kv0 + 64, cur ^ 1);
            asm volatile("s_waitcnt vmcnt(2)" ::: "memory");
        } else {
            asm volatile("s_waitcnt vmcnt(0)" ::: "memory");
        }
        __builtin_amdgcn_s_barrier();
        asm volatile("" ::: "memory");

        if (kv0 <= wq0 + 31) { // wave-uniform guard
            const unsigned short* Kb = lds + cur * 8192;
            const unsigned short* Vb = lds + cur * 8192 + 4096;
            const bool diag = (kv0 + 63) > wq0;
            __builtin_amdgcn_s_setprio(1);
#pragma unroll
            for (int kk = 0; kk < 2; kk++) {
                f32x16 sc = zero16();
                const unsigned short* krow = Kb + (kk * 32 + l31) * 64;
#pragma unroll
                for (int s = 0; s < 4; s++) {
                    bf16x8 kf = *reinterpret_cast<const bf16x8*>(krow + ((2 * s + hi) ^ sx) * 8);
                    sc = mfma32(kf, qf[s], sc);
                }
                const int kvkk = kv0 + kk * 32 + 4 * hi;
                unsigned int wd[4][2];
#pragma unroll
                for (int i = 0; i < 16; i += 2) {
                    float p0 = __builtin_amdgcn_exp2f(sc[i]);
                    float p1 = __builtin_amdgcn_exp2f(sc[i + 1]);
                    if (diag) {
                        int kg = kvkk + (i & 3) + 8 * (i >> 2);
                        p0 = (kg > qg) ? 0.f : p0;
                        p1 = (kg + 1 > qg) ? 0.f : p1;
                    }
                    lsum += p0 + p1;
                    unsigned int wv;
                    asm("v_cvt_pk_bf16_f32 %0, %1, %2" : "=v"(wv) : "v"(p0), "v"(p1));
                    wd[i >> 2][(i >> 1) & 1] = wv;
                }
#pragma unroll
                for (int s = 0; s < 2; s++) {
                    uivec2 r0 = __builtin_amdgcn_permlane32_swap(wd[2 * s][0], wd[2 * s + 1][0],
                                                                 false, false);
                    uivec2 r1 = __builtin_amdgcn_permlane32_swap(wd[2 * s][1], wd[2 * s + 1][1],
                                                                 false, false);
                    uivec4 frv = {r0.x, r1.x, r0.y, r1.y};
                    bf16x8 pfrag = __builtin_bit_cast(bf16x8, frv);
                    const int ks = kk * 2 + s;
#pragma unroll
                    for (int dt = 0; dt < 2; dt++) {
                        bf16x8 vf = *reinterpret_cast<const bf16x8*>(
                            Vb + (dt * 32 + l31) * 64 + ((2 * ks + hi) ^ sx) * 8);
                        accO[dt] = mfma32(vf, pfrag, accO[dt]);
                    }
                }
            }
            __builtin_amdgcn_s_setprio(0);
        }
        asm volatile("" ::: "memory");
        __builtin_amdgcn_s_barrier();
    }
#undef STAGE

    __syncthreads();
    float lt = lsum + __shfl_xor(lsum, 32, 64);
    float linv = 1.0f / lt;
    unsigned int* ow = (unsigned int*)lds + w * 1024;
#pragma unroll
    for (int dt = 0; dt < 2; dt++) {
#pragma unroll
        for (int i = 0; i < 16; i += 2) {
            float v0 = accO[dt][i] * linv;
            float v1 = accO[dt][i + 1] * linv;
            unsigned int wv;
            asm("v_cvt_pk_bf16_f32 %0, %1, %2" : "=v"(wv) : "v"(v0), "v"(v1));
            int idx = ((i & 3) + 8 * (i >> 2) + 4 * hi + 32 * dt) >> 1;
            ow[l31 * 32 + (idx ^ (sx << 2))] = wv;
        }
    }
    int q2 = lane >> 1;
    int c0 = (lane & 1) * 4;
    unsigned short* orow = attn_out + (size_t)(b * T_SZ + wq0 + q2) * C_SZ + h * D_SZ;
#pragma unroll
    for (int j = 0; j < 4; j++) {
        int c = c0 + j;
        uint4 val = *(const uint4*)(ow + q2 * 32 + ((c ^ (q2 & 7)) * 4));
        *(uint4*)(orow + c * 8) = val;
    }
}

extern "C" void kernel_launch(void* const* d_in, const int* in_sizes, int n_in,
                              void* d_out, int out_size, void* d_ws, size_t ws_size,
                              hipStream_t stream) {
    (void)in_sizes; (void)n_in; (void)out_size;
    const float* x     = (const float*)d_in[0];
    const float* w_qkv = (const float*)d_in[1];
    const float* b_qkv = (const float*)d_in[2];
    const float* w_out = (const float*)d_in[3];
    const float* b_out = (const float*)d_in[4];
    float* out = (float*)d_out;

    unsigned short* xb    = (unsigned short*)d_ws;            // M x C
    unsigned short* wqkvT = xb + (size_t)M_SZ * C_SZ;         // N3 x C
    unsigned short* woutT = wqkvT + (size_t)N3_SZ * C_SZ;     // C x C
    unsigned short* qp    = woutT + (size_t)C_SZ * C_SZ;      // M x C (Q plane)
    unsigned short* kpp   = qp + (size_t)M_SZ * C_SZ;         // M x C (K plane)
    unsigned short* vtp   = kpp + (size_t)M_SZ * C_SZ;        // BH x 64 x T (Vt plane)
    unsigned short* attn  = vtp + (size_t)M_SZ * C_SZ;        // M x C
    float* rtab = (float*)(attn + (size_t)M_SZ * C_SZ);       // T x 64 (cos/sin interleaved)
    size_t needed = (size_t)((char*)(rtab + T_SZ * 64) - (char*)d_ws);
    if (ws_size < needed) return;

    hipFuncSetAttribute((const void*)k_gemmqkv,
                        hipFuncAttributeMaxDynamicSharedMemorySize, 73728);
    hipFuncSetAttribute((const void*)k_gemmout,
                        hipFuncAttributeMaxDynamicSharedMemorySize, 73728);

    k_prologue<<<2048 + 3072 + 1024 + 256, 256, 0, stream>>>(
        (const float4*)x, (uint2*)xb, w_qkv, wqkvT, w_out, woutT, rtab);
    k_gemmqkv<<<dim3(12, 64), 512, 73728, stream>>>(xb, wqkvT, b_qkv, qp, kpp, vtp, rtab);
    k_attn<<<dim3(8, 64), 512, 0, stream>>>(qp, kpp, vtp, attn);
    k_gemmout<<<dim3(4, 64), 512, 73728, stream>>>(attn, woutT, b_out, out);
}